// Round 11
// baseline (618.098 us; speedup 1.0000x reference)
//
#include <hip/hip_runtime.h>
#include <cstddef>

// Problem constants
#define NN_ 4096      // nodes
#define TT_ 64        // tokens per node
#define DIN 300       // embedding dim
#define DINP 320      // padded to mult of 32
#define RH_ 256       // rnn hidden
#define G3_ 768       // 3*RH
#define BB_ 64        // graphs
#define EE_ 65536     // edges

typedef short bf16x8 __attribute__((ext_vector_type(8)));
typedef float f32x4 __attribute__((ext_vector_type(4)));
typedef unsigned short u16;
typedef unsigned short u16x4 __attribute__((ext_vector_type(4)));

__device__ __forceinline__ u16 f2bf(float f) {
    unsigned u = __builtin_bit_cast(unsigned, f);
    u += 0x7fff + ((u >> 16) & 1);          // RNE
    return (u16)(u >> 16);
}
__device__ __forceinline__ float bf2f(u16 v) {
    return __builtin_bit_cast(float, (unsigned)v << 16);
}

__device__ __forceinline__ void gload16(const void* g, void* l) {
    __builtin_amdgcn_global_load_lds(
        (const __attribute__((address_space(1))) unsigned*)g,
        (__attribute__((address_space(3))) unsigned*)l, 16, 0, 0);
}

#define MFMA16 __builtin_amdgcn_mfma_f32_16x16x32_bf16

// ---------------- zero fill ----------------
__global__ void k_zero(float* __restrict__ p, long n) {
    for (long i = (long)blockIdx.x * blockDim.x + threadIdx.x; i < n;
         i += (long)gridDim.x * blockDim.x)
        p[i] = 0.f;
}

// ---------------- f32 -> bf16 convert with column pad ----------------
__global__ void k_cvt(const float* __restrict__ src, u16* __restrict__ dst,
                      int R, int C, int Cp) {
    long total = (long)R * Cp;
    for (long i = (long)blockIdx.x * blockDim.x + threadIdx.x; i < total;
         i += (long)gridDim.x * blockDim.x) {
        int r = (int)(i / Cp);
        int c = (int)(i - (long)r * Cp);
        dst[i] = (c < C) ? f2bf(src[(size_t)r * C + c]) : (u16)0;
    }
}

// ---------------- W [K][256] f32 -> Wt [256][K] bf16 (transpose+convert) ----
__global__ void k_cvtT(const float* __restrict__ W, u16* __restrict__ Wt, int K) {
    int total = 256 * K;
    for (int i = blockIdx.x * blockDim.x + threadIdx.x; i < total;
         i += gridDim.x * blockDim.x) {
        int c = i / K, k = i - c * K;
        Wt[i] = f2bf(W[(size_t)k * 256 + c]);
    }
}

// ---------------- build block-diagonal adjacency counts ----------------
__global__ void k_buildA(const int* __restrict__ src, const int* __restrict__ dst,
                         float* __restrict__ A) {
    int e = blockIdx.x * blockDim.x + threadIdx.x;
    if (e < EE_) {
        int g = src[e] >> 6, i = dst[e] & 63, j = src[e] & 63;
        atomicAdd(&A[(((g << 6) + i) << 6) + j], 1.f);
    }
}

// ---------------- transpose + convert: h f32 [4096][C] -> hT bf16 [C][4096] --
__global__ __launch_bounds__(256) void k_trans(const float* __restrict__ h, int C,
                                               u16* __restrict__ hT) {
    __shared__ u16 Ls[64][72];
    int r0 = blockIdx.x * 64, c0 = blockIdx.y * 64;
    int tid = threadIdx.x;
    int r = tid >> 2, cq = tid & 3;
#pragma unroll
    for (int i = 0; i < 4; i++) {
        float4 v = *(const float4*)(h + (size_t)(r0 + r) * C + c0 + cq * 16 + i * 4);
        Ls[r][cq * 16 + i * 4 + 0] = f2bf(v.x);
        Ls[r][cq * 16 + i * 4 + 1] = f2bf(v.y);
        Ls[r][cq * 16 + i * 4 + 2] = f2bf(v.z);
        Ls[r][cq * 16 + i * 4 + 3] = f2bf(v.w);
    }
    __syncthreads();
    int c = tid >> 2, rq = tid & 3;
    u16 tmp[16];
#pragma unroll
    for (int i = 0; i < 16; i++) tmp[i] = Ls[rq * 16 + i][c];
    u16* o = hT + (size_t)(c0 + c) * NN_ + r0 + rq * 16;
    *(uint4*)o = ((const uint4*)tmp)[0];
    *(uint4*)(o + 8) = ((const uint4*)tmp)[1];
}

// ---------------- XP2 = emb @ Wx^T + biases -> bf16, layout [V][256][4] -----
// slot: 0=r(+bhh), 1=z(+bhh), 2=n(bih only), 3=pad. Grid (500, 12).
// (verified in Round 6: passed with absmax 7.8e-3)
__global__ __launch_bounds__(256) void k_xproj(
    const u16* __restrict__ embbf, const u16* __restrict__ Wx,
    const float* __restrict__ bih, const float* __restrict__ bhh,
    u16* __restrict__ XP2)
{
    __shared__ __align__(16) u16 As[2][64 * 32];
    __shared__ __align__(16) u16 Bs[2][64 * 32];
    const int tid = threadIdx.x;
    const int v0 = blockIdx.x * 64, c0 = blockIdx.y * 64;
    const int sr = tid >> 2, sq = tid & 3;
    const u16* pa = embbf + (size_t)(v0 + sr) * DINP + sq * 8;
    const u16* pb = Wx + (size_t)(c0 + sr) * DINP + sq * 8;

    const int lane = tid & 63, wave = tid >> 6;
    const int wr = wave >> 1, wc = wave & 1;
    const int l15 = lane & 15, l4 = lane >> 4;
    const int aoff = (wr * 32 + l15) * 32 + l4 * 8;
    const int boff = (wc * 32 + l15) * 32 + l4 * 8;
    f32x4 acc[2][2] = {};

    gload16(pa, &As[0][tid * 8]);
    gload16(pb, &Bs[0][tid * 8]);
    __syncthreads();
    constexpr int NSK = DINP / 32;   // 10
#pragma unroll
    for (int s = 0; s < NSK; s++) {
        if (s + 1 < NSK) {
            gload16(pa + (s + 1) * 32, &As[(s + 1) & 1][tid * 8]);
            gload16(pb + (s + 1) * 32, &Bs[(s + 1) & 1][tid * 8]);
        }
        const int b = s & 1;
        bf16x8 a0 = *(const bf16x8*)&As[b][aoff];
        bf16x8 a1 = *(const bf16x8*)&As[b][aoff + 512];
        bf16x8 b0 = *(const bf16x8*)&Bs[b][boff];
        bf16x8 b1 = *(const bf16x8*)&Bs[b][boff + 512];
        acc[0][0] = MFMA16(a0, b0, acc[0][0], 0, 0, 0);
        acc[0][1] = MFMA16(a0, b1, acc[0][1], 0, 0, 0);
        acc[1][0] = MFMA16(a1, b0, acc[1][0], 0, 0, 0);
        acc[1][1] = MFMA16(a1, b1, acc[1][1], 0, 0, 0);
        __syncthreads();
    }
#pragma unroll
    for (int fj = 0; fj < 2; fj++) {
        const int cf = c0 + wc * 32 + fj * 16 + l15;   // 0..767
        const int g = cf >> 8, c = cf & 255;
        const float bb = bih[cf] + (cf < 512 ? bhh[cf] : 0.f);
#pragma unroll
        for (int fi = 0; fi < 2; fi++)
#pragma unroll
            for (int rg = 0; rg < 4; rg++) {
                const int v = v0 + wr * 32 + fi * 16 + l4 * 4 + rg;
                XP2[((size_t)v * 256 + c) * 4 + g] = f2bf(acc[fi][fj][rg] + bb);
            }
    }
}

// ---------------- persistent GRU scan: 64 steps in one kernel ---------------
// 256 blocks x 512 threads (8 waves; wave owns 32 cols x 3 gates).
// R11 residency fix: Wh fragments enter registers via ds_read from an LDS
// buffer that is LATER OVERWRITTEN (reused for XP staging). ds_read results
// from clobbered LDS are NON-REMATERIALIZABLE -- unlike R5-R10's global
// loads -- so regalloc must keep the 192 VGPRs live (attn-kernel precedent:
// 205-249 VGPR at 512 threads). t-loop has ZERO weight loads.
// XP packed [16][256][4] in the shared 32 KB buffer -> one b64 read per cell.
// All LDS layouts XOR-swizzled with pre-swizzled DMA sources (rule 21).
__global__ __launch_bounds__(512, 2) void k_scan(
    const int* __restrict__ tokens,      // [4096][64]
    const u16* __restrict__ XP2,         // [32000][256][4]
    const u16* __restrict__ Wh,          // [768][256]
    const float* __restrict__ bhh,
    float* __restrict__ HA)              // [4096][512], writes cols 0..255
{
    __shared__ __align__(16) u16 hS[16 * RH_];   // 8 KB, swizzled
    __shared__ __align__(16) u16 SH[16384];      // 32 KB: Wh bounce, then XPs
    __shared__ int toks[16 * 68];                // padded rows

    const int tid = threadIdx.x;
    const int n0 = blockIdx.x * 16;
    const int lane = tid & 63, wave = tid >> 6;
    const int l15 = lane & 15, l4 = lane >> 4;
    const int c0w = wave * 32;

    // prologue: tokens -> LDS [row][68]; zero hS
    {
        int row = tid >> 5, tt = tid & 31;
        toks[row * 68 + tt]      = tokens[(n0 + row) * TT_ + tt];
        toks[row * 68 + 32 + tt] = tokens[(n0 + row) * TT_ + 32 + tt];
    }
    ((unsigned long long*)hS)[tid] = 0ull;
    ((unsigned long long*)hS)[512 + tid] = 0ull;
    __syncthreads();

    // ---- Wh -> registers via LDS bounce (12 rounds x 64 rows x 256 cols) ----
    // Stage chunk: LDS[rb][k5] = Wh[base+rb][k5 ^ (rb&7)]  (16B chunks)
    // Read: byte (row*512 + ks*64 + l4*16) ^ ((row&7)<<4)  -> orig fragment.
    bf16x8 Bv[3][2][8];
#pragma unroll
    for (int g = 0; g < 3; ++g) {
#pragma unroll
        for (int rr = 0; rr < 4; ++rr) {
            const int baseRow = g * 256 + rr * 64;
#pragma unroll
            for (int j = 0; j < 4; ++j) {
                int c = tid + j * 512;          // 0..2047
                int rb = c >> 5, k5 = c & 31;
                gload16(Wh + (size_t)(baseRow + rb) * 256 + (k5 ^ (rb & 7)) * 8,
                        SH + c * 8);
            }
            __syncthreads();                    // DMA drained, buffer ready
            if ((wave >> 1) == rr) {
                const int rb0 = (wave & 1) * 32;
#pragma unroll
                for (int f = 0; f < 2; ++f)
#pragma unroll
                    for (int ks = 0; ks < 8; ++ks) {
                        const int row = rb0 + f * 16 + l15;
                        const int ba = (row * 512 + ks * 64 + l4 * 16) ^ ((row & 7) << 4);
                        Bv[g][f][ks] = *(const bf16x8*)((const char*)SH + ba);
                    }
            }
            __syncthreads();                    // reads done before next stage
        }
    }

    const float bhn0 = bhh[512 + c0w + l15];
    const float bhn1 = bhh[512 + c0w + 16 + l15];

    // XP staging into SH as [16 rows][128 chunks of 16B], rows XOR-swizzled.
    auto STAGE_XP = [&](int t) {
#pragma unroll
        for (int j = 0; j < 4; ++j) {
            int c = tid + j * 512;               // 0..2047
            int row = c >> 7, k7 = c & 127;
            int tok = toks[row * 68 + t];
            gload16(XP2 + (size_t)tok * 1024 + (k7 ^ (row & 7)) * 8,
                    SH + c * 8);
        }
    };

    STAGE_XP(0);

    f32x4 hprev[2] = {};

#pragma unroll 1
    for (int t = 0; t < TT_; ++t) {
        // ---- recurrent GEMM: gh = h @ Wh^T (A from swizzled hS, B resident) ----
        f32x4 acc[3][2];
#pragma unroll
        for (int g = 0; g < 3; ++g) { acc[g][0] = f32x4{}; acc[g][1] = f32x4{}; }
#pragma unroll
        for (int ks = 0; ks < 8; ++ks) {
            const int aa = (l15 * 512 + ks * 64 + l4 * 16) ^ ((l15 & 7) << 4);
            bf16x8 a = *(const bf16x8*)((const char*)hS + aa);
#pragma unroll
            for (int g = 0; g < 3; ++g) {
                acc[g][0] = MFMA16(a, Bv[g][0][ks], acc[g][0], 0, 0, 0);
                acc[g][1] = MFMA16(a, Bv[g][1][ks], acc[g][1], 0, 0, 0);
            }
        }
        __syncthreads();   // hS reads done; XP DMA for step t drained+visible

        // ---- gate math: one b64 read per cell from packed swizzled SH ----
#pragma unroll
        for (int f = 0; f < 2; ++f) {
            const int cc = c0w + f * 16 + l15;     // 0..255
            const float bhn = f == 0 ? bhn0 : bhn1;
#pragma unroll
            for (int rg = 0; rg < 4; ++rg) {
                const int r = l4 * 4 + rg;
                const int xa = (r * 2048 + cc * 8) ^ ((r & 7) << 4);
                u16x4 xv = *(const u16x4*)((const char*)SH + xa);
                float xr = bf2f(xv[0]);
                float xz = bf2f(xv[1]);
                float xn = bf2f(xv[2]);
                float rr = 1.f / (1.f + __expf(-(xr + acc[0][f][rg])));
                float zz = 1.f / (1.f + __expf(-(xz + acc[1][f][rg])));
                float pre = xn + rr * (acc[2][f][rg] + bhn);
                float nv = 2.f / (1.f + __expf(-2.f * pre)) - 1.f;
                float hnew = nv + zz * (hprev[f][rg] - nv);
                hprev[f][rg] = hnew;
                if (t < TT_ - 1) {
                    const int ba = (r * 512 + cc * 2) ^ ((r & 7) << 4);
                    *(u16*)((char*)hS + ba) = f2bf(hnew);
                } else {
                    HA[(size_t)(n0 + r) * 512 + cc] = hnew;
                }
            }
        }
        __syncthreads();   // SH/hS consumers done; issue next-step DMA after
        if (t + 1 < TT_) STAGE_XP(t + 1);
    }
}

// ---------------- backward GRU single cell (x-part only, h0=0) --------------
template<bool XONLY>
__global__ __launch_bounds__(256) void k_step(
    const int* __restrict__ tokens, int t,
    const u16* __restrict__ embbf, const u16* __restrict__ Wx,
    const u16* __restrict__ Wh,
    const float* __restrict__ bih, const float* __restrict__ bhh,
    const u16* __restrict__ hbf_in, const float* __restrict__ hf_in,
    float* __restrict__ outf, int ostride, u16* __restrict__ outbf)
{
    constexpr int NSX = DINP / 32;
    constexpr int NS  = XONLY ? NSX : NSX + RH_ / 32;

    __shared__ __align__(16) u16 As[2][32 * 32];
    __shared__ __align__(16) u16 Bs[2][3 * 64 * 32];

    const int tid = threadIdx.x;
    const int n0 = blockIdx.x * 32;
    const int c0 = blockIdx.y * 64;

    const int sr = tid >> 2;
    const int sq = tid & 3;
    const int tok = (tid < 128) ? tokens[(n0 + sr) * TT_ + t] : 0;
    const u16* ax  = embbf + (size_t)tok * DINP + sq * 8;
    const u16* ah  = XONLY ? ax : hbf_in + (size_t)(n0 + sr) * RH_ + sq * 8;
    const u16* bx0 = Wx + (size_t)(0 * 256 + c0 + sr) * DINP + sq * 8;
    const u16* bx1 = Wx + (size_t)(1 * 256 + c0 + sr) * DINP + sq * 8;
    const u16* bx2 = Wx + (size_t)(2 * 256 + c0 + sr) * DINP + sq * 8;
    const u16* bh0 = XONLY ? ax : Wh + (size_t)(0 * 256 + c0 + sr) * RH_ + sq * 8;
    const u16* bh1 = XONLY ? ax : Wh + (size_t)(1 * 256 + c0 + sr) * RH_ + sq * 8;
    const u16* bh2 = XONLY ? ax : Wh + (size_t)(2 * 256 + c0 + sr) * RH_ + sq * 8;

    auto STAGE = [&](int b, int s) {
        u16* db = &Bs[b][tid * 8];
        if (s < NSX) {
            int kk = s * 32;
            if (tid < 128) gload16(ax + kk, &As[b][tid * 8]);
            gload16(bx0 + kk, db);
            gload16(bx1 + kk, db + 2048);
            gload16(bx2 + kk, db + 4096);
        } else {
            int kk = (s - NSX) * 32;
            if (tid < 128) gload16(ah + kk, &As[b][tid * 8]);
            gload16(bh0 + kk, db);
            gload16(bh1 + kk, db + 2048);
            gload16(bh2 + kk, db + 4096);
        }
    };

    const int lane = tid & 63;
    const int wave = tid >> 6;
    const int wr = wave >> 1, wc = wave & 1;
    const int l15 = lane & 15, l4 = lane >> 4;

    f32x4 aR[2] = {}, aZ[2] = {}, aXN[2] = {}, aHN[2] = {};

    const int aoff = (wr * 16 + l15) * 32 + l4 * 8;
    const int boff = (wc * 32 + l15) * 32 + l4 * 8;

    auto COMPUTE = [&](int b, bool xp) {
        bf16x8 a0 = *(const bf16x8*)&As[b][aoff];
        const u16* B = &Bs[b][0];
        bf16x8 r0 = *(const bf16x8*)&B[boff];
        bf16x8 r1 = *(const bf16x8*)&B[boff + 512];
        bf16x8 z0 = *(const bf16x8*)&B[2048 + boff];
        bf16x8 z1 = *(const bf16x8*)&B[2048 + boff + 512];
        bf16x8 n0f = *(const bf16x8*)&B[4096 + boff];
        bf16x8 n1f = *(const bf16x8*)&B[4096 + boff + 512];
        aR[0] = MFMA16(a0, r0, aR[0], 0, 0, 0);
        aR[1] = MFMA16(a0, r1, aR[1], 0, 0, 0);
        aZ[0] = MFMA16(a0, z0, aZ[0], 0, 0, 0);
        aZ[1] = MFMA16(a0, z1, aZ[1], 0, 0, 0);
        if (xp) {
            aXN[0] = MFMA16(a0, n0f, aXN[0], 0, 0, 0);
            aXN[1] = MFMA16(a0, n1f, aXN[1], 0, 0, 0);
        } else {
            aHN[0] = MFMA16(a0, n0f, aHN[0], 0, 0, 0);
            aHN[1] = MFMA16(a0, n1f, aHN[1], 0, 0, 0);
        }
    };

    STAGE(0, 0);
    __syncthreads();
#pragma unroll
    for (int s = 0; s < NS; ++s) {
        if (s + 1 < NS) STAGE((s + 1) & 1, s + 1);
        COMPUTE(s & 1, s < NSX);
        __syncthreads();
    }

#pragma unroll
    for (int fj = 0; fj < 2; ++fj) {
        const int c = c0 + wc * 32 + fj * 16 + l15;
        const float bR  = bih[c] + bhh[c];
        const float bZ  = bih[256 + c] + bhh[256 + c];
        const float bXN = bih[512 + c];
        const float bHN = bhh[512 + c];
#pragma unroll
        for (int rg = 0; rg < 4; ++rg) {
            const int n = n0 + wr * 16 + l4 * 4 + rg;
            float r  = 1.f / (1.f + __expf(-(aR[fj][rg] + bR)));
            float z  = 1.f / (1.f + __expf(-(aZ[fj][rg] + bZ)));
            float pre = aXN[fj][rg] + bXN + r * (aHN[fj][rg] + bHN);
            float nv = 2.f / (1.f + __expf(-2.f * pre)) - 1.f;
            float hp = XONLY ? 0.f : hf_in[(size_t)n * RH_ + c];
            float h  = (1.f - z) * nv + z * hp;
            outf[(size_t)n * ostride + c] = h;
            if (!XONLY) outbf[(size_t)n * RH_ + c] = f2bf(h);
        }
    }
}

// ---------------- block-diag aggregation: agg_g = A_g @ h_g (bf16 MFMA) -----
__global__ __launch_bounds__(256) void k_agg(
    const u16* __restrict__ Abf, const u16* __restrict__ hT,
    u16* __restrict__ aggbf, int C)
{
    const int g = blockIdx.x, ct = blockIdx.y;
    const int lane = threadIdx.x & 63, wave = threadIdx.x >> 6;
    const int wi = wave >> 1, wcC = wave & 1;
    const int l15 = lane & 15, l4 = lane >> 4;
    f32x4 acc[2][2] = {};
#pragma unroll
    for (int kc = 0; kc < 2; kc++) {
        bf16x8 af[2], bf_[2];
#pragma unroll
        for (int fi = 0; fi < 2; fi++)
            af[fi] = *(const bf16x8*)(Abf + ((size_t)g * 64 + wi * 32 + fi * 16 + l15) * 64
                                      + kc * 32 + l4 * 8);
#pragma unroll
        for (int fj = 0; fj < 2; fj++)
            bf_[fj] = *(const bf16x8*)(hT + (size_t)(ct * 64 + wcC * 32 + fj * 16 + l15) * NN_
                                       + g * 64 + kc * 32 + l4 * 8);
#pragma unroll
        for (int fi = 0; fi < 2; fi++)
#pragma unroll
            for (int fj = 0; fj < 2; fj++)
                acc[fi][fj] = MFMA16(af[fi], bf_[fj], acc[fi][fj], 0, 0, 0);
    }
#pragma unroll
    for (int fi = 0; fi < 2; fi++)
#pragma unroll
        for (int fj = 0; fj < 2; fj++)
#pragma unroll
            for (int rg = 0; rg < 4; rg++) {
                int n = g * 64 + wi * 32 + fi * 16 + l4 * 4 + rg;
                int c = ct * 64 + wcC * 32 + fj * 16 + l15;
                aggbf[(size_t)n * C + c] = f2bf(acc[fi][fj][rg]);
            }
}

// ---------------- GCN GEMM (bf16 MFMA): out = relu(agg @ W + b) -------------
template<int K>
__global__ __launch_bounds__(256) void k_gcnM(
    const u16* __restrict__ Ag, const u16* __restrict__ Wt,
    const float* __restrict__ bias, float* __restrict__ outF)
{
    __shared__ __align__(16) u16 As[2][64 * 32];
    __shared__ __align__(16) u16 Bs[2][64 * 32];
    const int tid = threadIdx.x;
    const int n0 = blockIdx.x * 64, c0 = blockIdx.y * 64;
    const int sr = tid >> 2, sq = tid & 3;
    const u16* pa = Ag + (size_t)(n0 + sr) * K + sq * 8;
    const u16* pb = Wt + (size_t)(c0 + sr) * K + sq * 8;

    const int lane = tid & 63, wave = tid >> 6;
    const int wr = wave >> 1, wc = wave & 1;
    const int l15 = lane & 15, l4 = lane >> 4;
    const int aoff = (wr * 32 + l15) * 32 + l4 * 8;
    const int boff = (wc * 32 + l15) * 32 + l4 * 8;
    f32x4 acc[2][2] = {};

    gload16(pa, &As[0][tid * 8]);
    gload16(pb, &Bs[0][tid * 8]);
    __syncthreads();
    constexpr int NSK = K / 32;
#pragma unroll
    for (int s = 0; s < NSK; s++) {
        if (s + 1 < NSK) {
            gload16(pa + (s + 1) * 32, &As[(s + 1) & 1][tid * 8]);
            gload16(pb + (s + 1) * 32, &Bs[(s + 1) & 1][tid * 8]);
        }
        const int b = s & 1;
        bf16x8 a0 = *(const bf16x8*)&As[b][aoff];
        bf16x8 a1 = *(const bf16x8*)&As[b][aoff + 512];
        bf16x8 b0 = *(const bf16x8*)&Bs[b][boff];
        bf16x8 b1 = *(const bf16x8*)&Bs[b][boff + 512];
        acc[0][0] = MFMA16(a0, b0, acc[0][0], 0, 0, 0);
        acc[0][1] = MFMA16(a0, b1, acc[0][1], 0, 0, 0);
        acc[1][0] = MFMA16(a1, b0, acc[1][0], 0, 0, 0);
        acc[1][1] = MFMA16(a1, b1, acc[1][1], 0, 0, 0);
        __syncthreads();
    }
#pragma unroll
    for (int fj = 0; fj < 2; fj++) {
        const int c = c0 + wc * 32 + fj * 16 + l15;
        const float bb = bias[c];
#pragma unroll
        for (int fi = 0; fi < 2; fi++)
#pragma unroll
            for (int rg = 0; rg < 4; rg++) {
                const int n = n0 + wr * 32 + fi * 16 + l4 * 4 + rg;
                outF[(size_t)n * 256 + c] = fmaxf(acc[fi][fj][rg] + bb, 0.f);
            }
    }
}

// ---------------- readout ----------------
__global__ void k_readout(const float* __restrict__ h, const int* __restrict__ gid,
                          const int* __restrict__ ntype, float* __restrict__ out,
                          float* __restrict__ cnt)
{
    for (int idx = blockIdx.x * blockDim.x + threadIdx.x; idx < NN_ * 256;
         idx += gridDim.x * blockDim.x) {
        int n = idx >> 8, c = idx & 255;
        float v = h[idx];
        int g = gid[n], t = ntype[n];
        if (t == 0) {
            atomicAdd(&out[g * 256 + c], v);
            if (c == 0) atomicAdd(&cnt[g], 1.f);
        } else if (t == 1) {
            atomicAdd(&out[16384 + g * 256 + c], v);
        } else {
            atomicAdd(&out[32768 + g * 256 + c], v);
        }
    }
}

__global__ void k_finalize(float* __restrict__ out, const float* __restrict__ cnt)
{
    int idx = blockIdx.x * blockDim.x + threadIdx.x;  // < 16384
    out[idx] /= cnt[idx >> 8];
}

// ---------------- host ----------------
extern "C" void kernel_launch(void* const* d_in, const int* in_sizes, int n_in,
                              void* d_out, int out_size, void* d_ws, size_t ws_size,
                              hipStream_t stream)
{
    const int*   tokens = (const int*)d_in[0];
    const int*   esrc   = (const int*)d_in[1];
    const int*   edst   = (const int*)d_in[2];
    const int*   gid    = (const int*)d_in[3];
    const int*   ntype  = (const int*)d_in[4];
    const float* emb    = (const float*)d_in[5];
    const float* W_ih_f = (const float*)d_in[6];
    const float* W_hh_f = (const float*)d_in[7];
    const float* b_ih_f = (const float*)d_in[8];
    const float* b_hh_f = (const float*)d_in[9];
    const float* W_ih_b = (const float*)d_in[10];
    const float* b_ih_b = (const float*)d_in[12];
    const float* b_hh_b = (const float*)d_in[13];
    const float* Wg[4]  = {(const float*)d_in[14], (const float*)d_in[16],
                           (const float*)d_in[18], (const float*)d_in[20]};
    const float* bg[4]  = {(const float*)d_in[15], (const float*)d_in[17],
                           (const float*)d_in[19], (const float*)d_in[21]};
    float* out = (float*)d_out;

    // workspace layout (16B aligned).
    // Af overlays hF (Af: prologue only; hF first written after scan).
    // hT + aggb overlay XP2's head (XP2 dead after k_scan).
    float* hF    = (float*)d_ws;                        // [4096][256] f32
    float* Af    = hF;                                  // [64][64][64] f32 (prologue)
    u16*   embbf = (u16*)(hF + (size_t)NN_ * RH_);      // [32000][320]
    u16*   wxf   = embbf + 32000L * DINP;               // [768][320]
    u16*   whf   = wxf + (size_t)G3_ * DINP;            // [768][256]
    u16*   wxb   = whf + (size_t)G3_ * RH_;             // [768][320]
    u16*   wtg   = wxb + (size_t)G3_ * DINP;            // [256][512] max
    u16*   Abf   = wtg + 256L * 512;                    // [64][64][64]
    u16*   XP2   = Abf + 64L * 64 * 64;                 // [32000][256][4]
    u16*   hT    = XP2;                                 // [512][4096] (post-scan)
    u16*   aggb  = hT + 512L * NN_;                     // [4096][512] (post-scan)
    float* HA    = (float*)(XP2 + 32000L * 1024);       // [4096][512] f32
    float* CNT   = HA + (size_t)NN_ * 512;              // [64]

    // one-time conversions + adjacency build
    k_cvt<<<2048, 256, 0, stream>>>(emb, embbf, 32000, DIN, DINP);
    k_cvt<<<256, 256, 0, stream>>>(W_ih_f, wxf, G3_, DIN, DINP);
    k_cvt<<<256, 256, 0, stream>>>(W_hh_f, whf, G3_, RH_, RH_);
    k_cvt<<<256, 256, 0, stream>>>(W_ih_b, wxb, G3_, DIN, DINP);
    k_zero<<<256, 256, 0, stream>>>(Af, 64L * 64 * 64);
    k_buildA<<<256, 256, 0, stream>>>(esrc, edst, Af);
    k_cvt<<<256, 256, 0, stream>>>(Af, Abf, 64 * 64, 64, 64);

    // XP2 table then the whole forward scan in ONE kernel
    k_xproj<<<dim3(500, 12), 256, 0, stream>>>(embbf, wxf, b_ih_f, b_hh_f, XP2);
    k_scan<<<256, 512, 0, stream>>>(tokens, XP2, whf, b_hh_f, HA);

    // backward GRU single cell on x[:,T-1] -> HA cols 256..511
    k_step<true><<<dim3(128, 4), 256, 0, stream>>>(
        tokens, TT_ - 1, embbf, wxb, nullptr, b_ih_b, b_hh_b,
        nullptr, nullptr, HA + 256, 512, nullptr);

    // GCN: hT <- transpose(h); agg <- blockdiag(A) @ h; h <- relu(agg @ W + b)
    k_trans<<<dim3(64, 8), 256, 0, stream>>>(HA, 512, hT);
    for (int l = 0; l < 4; l++) {
        int K = (l == 0) ? 512 : 256;
        k_cvtT<<<128, 256, 0, stream>>>(Wg[l], wtg, K);
        k_agg<<<dim3(64, K / 64), 256, 0, stream>>>(Abf, hT, aggb, K);
        if (K == 512)
            k_gcnM<512><<<dim3(64, 4), 256, 0, stream>>>(aggb, wtg, bg[l], hF);
        else
            k_gcnM<256><<<dim3(64, 4), 256, 0, stream>>>(aggb, wtg, bg[l], hF);
        if (l < 3) k_trans<<<dim3(64, 4), 256, 0, stream>>>(hF, 256, hT);
    }

    // readout
    k_zero<<<256, 256, 0, stream>>>(out, 49152);
    k_zero<<<1, 64, 0, stream>>>(CNT, 64);
    k_readout<<<2048, 256, 0, stream>>>(hF, gid, ntype, out, CNT);
    k_finalize<<<64, 256, 0, stream>>>(out, CNT);
}

// Round 12
// 447.223 us; speedup vs baseline: 1.3821x; 1.3821x over previous
//
#include <hip/hip_runtime.h>
#include <cstddef>

// Problem constants
#define NN_ 4096      // nodes
#define TT_ 64        // tokens per node
#define DIN 300       // embedding dim
#define DINP 320      // padded to mult of 32
#define RH_ 256       // rnn hidden
#define G3_ 768       // 3*RH
#define BB_ 64        // graphs
#define EE_ 65536     // edges

typedef short bf16x8 __attribute__((ext_vector_type(8)));
typedef float f32x4 __attribute__((ext_vector_type(4)));
typedef unsigned u32x4v __attribute__((ext_vector_type(4)));
typedef unsigned short u16;

__device__ __forceinline__ u16 f2bf(float f) {
    unsigned u = __builtin_bit_cast(unsigned, f);
    u += 0x7fff + ((u >> 16) & 1);          // RNE
    return (u16)(u >> 16);
}
__device__ __forceinline__ float bf2f(u16 v) {
    return __builtin_bit_cast(float, (unsigned)v << 16);
}

__device__ __forceinline__ void gload16(const void* g, void* l) {
    __builtin_amdgcn_global_load_lds(
        (const __attribute__((address_space(1))) unsigned*)g,
        (__attribute__((address_space(3))) unsigned*)l, 16, 0, 0);
}

#define MFMA16 __builtin_amdgcn_mfma_f32_16x16x32_bf16

// ---------------- zero fill ----------------
__global__ void k_zero(float* __restrict__ p, long n) {
    for (long i = (long)blockIdx.x * blockDim.x + threadIdx.x; i < n;
         i += (long)gridDim.x * blockDim.x)
        p[i] = 0.f;
}

// ---------------- f32 -> bf16 convert with column pad ----------------
__global__ void k_cvt(const float* __restrict__ src, u16* __restrict__ dst,
                      int R, int C, int Cp) {
    long total = (long)R * Cp;
    for (long i = (long)blockIdx.x * blockDim.x + threadIdx.x; i < total;
         i += (long)gridDim.x * blockDim.x) {
        int r = (int)(i / Cp);
        int c = (int)(i - (long)r * Cp);
        dst[i] = (c < C) ? f2bf(src[(size_t)r * C + c]) : (u16)0;
    }
}

// ---------------- W [K][256] f32 -> Wt [256][K] bf16 (transpose+convert) ----
__global__ void k_cvtT(const float* __restrict__ W, u16* __restrict__ Wt, int K) {
    int total = 256 * K;
    for (int i = blockIdx.x * blockDim.x + threadIdx.x; i < total;
         i += gridDim.x * blockDim.x) {
        int c = i / K, k = i - c * K;
        Wt[i] = f2bf(W[(size_t)k * 256 + c]);
    }
}

// ---------------- build block-diagonal adjacency counts ----------------
__global__ void k_buildA(const int* __restrict__ src, const int* __restrict__ dst,
                         float* __restrict__ A) {
    int e = blockIdx.x * blockDim.x + threadIdx.x;
    if (e < EE_) {
        int g = src[e] >> 6, i = dst[e] & 63, j = src[e] & 63;
        atomicAdd(&A[(((g << 6) + i) << 6) + j], 1.f);
    }
}

// ---------------- transpose + convert: h f32 [4096][C] -> hT bf16 [C][4096] --
__global__ __launch_bounds__(256) void k_trans(const float* __restrict__ h, int C,
                                               u16* __restrict__ hT) {
    __shared__ u16 Ls[64][72];
    int r0 = blockIdx.x * 64, c0 = blockIdx.y * 64;
    int tid = threadIdx.x;
    int r = tid >> 2, cq = tid & 3;
#pragma unroll
    for (int i = 0; i < 4; i++) {
        float4 v = *(const float4*)(h + (size_t)(r0 + r) * C + c0 + cq * 16 + i * 4);
        Ls[r][cq * 16 + i * 4 + 0] = f2bf(v.x);
        Ls[r][cq * 16 + i * 4 + 1] = f2bf(v.y);
        Ls[r][cq * 16 + i * 4 + 2] = f2bf(v.z);
        Ls[r][cq * 16 + i * 4 + 3] = f2bf(v.w);
    }
    __syncthreads();
    int c = tid >> 2, rq = tid & 3;
    u16 tmp[16];
#pragma unroll
    for (int i = 0; i < 16; i++) tmp[i] = Ls[rq * 16 + i][c];
    u16* o = hT + (size_t)(c0 + c) * NN_ + r0 + rq * 16;
    *(uint4*)o = ((const uint4*)tmp)[0];
    *(uint4*)(o + 8) = ((const uint4*)tmp)[1];
}

// ---------------- XPROJ = emb @ Wx^T + bih (+bhh for r,z cols) -> bf16 ------
// [32000][320] @ [768][320]^T -> [32000][768]. Grid (500, 12), BM=BN=64.
__global__ __launch_bounds__(256) void k_xproj(
    const u16* __restrict__ embbf, const u16* __restrict__ Wx,
    const float* __restrict__ bih, const float* __restrict__ bhh,
    u16* __restrict__ XP)
{
    __shared__ __align__(16) u16 As[2][64 * 32];
    __shared__ __align__(16) u16 Bs[2][64 * 32];
    const int tid = threadIdx.x;
    const int v0 = blockIdx.x * 64, c0 = blockIdx.y * 64;
    const int sr = tid >> 2, sq = tid & 3;
    const u16* pa = embbf + (size_t)(v0 + sr) * DINP + sq * 8;
    const u16* pb = Wx + (size_t)(c0 + sr) * DINP + sq * 8;

    const int lane = tid & 63, wave = tid >> 6;
    const int wr = wave >> 1, wc = wave & 1;
    const int l15 = lane & 15, l4 = lane >> 4;
    const int aoff = (wr * 32 + l15) * 32 + l4 * 8;
    const int boff = (wc * 32 + l15) * 32 + l4 * 8;
    f32x4 acc[2][2] = {};

    gload16(pa, &As[0][tid * 8]);
    gload16(pb, &Bs[0][tid * 8]);
    __syncthreads();
    constexpr int NSK = DINP / 32;   // 10
#pragma unroll
    for (int s = 0; s < NSK; s++) {
        if (s + 1 < NSK) {
            gload16(pa + (s + 1) * 32, &As[(s + 1) & 1][tid * 8]);
            gload16(pb + (s + 1) * 32, &Bs[(s + 1) & 1][tid * 8]);
        }
        const int b = s & 1;
        bf16x8 a0 = *(const bf16x8*)&As[b][aoff];
        bf16x8 a1 = *(const bf16x8*)&As[b][aoff + 512];
        bf16x8 b0 = *(const bf16x8*)&Bs[b][boff];
        bf16x8 b1 = *(const bf16x8*)&Bs[b][boff + 512];
        acc[0][0] = MFMA16(a0, b0, acc[0][0], 0, 0, 0);
        acc[0][1] = MFMA16(a0, b1, acc[0][1], 0, 0, 0);
        acc[1][0] = MFMA16(a1, b0, acc[1][0], 0, 0, 0);
        acc[1][1] = MFMA16(a1, b1, acc[1][1], 0, 0, 0);
        __syncthreads();
    }
#pragma unroll
    for (int fj = 0; fj < 2; fj++) {
        const int c = c0 + wc * 32 + fj * 16 + l15;   // 0..767
        const float bb = bih[c] + (c < 512 ? bhh[c] : 0.f);
#pragma unroll
        for (int fi = 0; fi < 2; fi++)
#pragma unroll
            for (int rg = 0; rg < 4; rg++) {
                const int v = v0 + wr * 32 + fi * 16 + l4 * 4 + rg;
                XP[(size_t)v * G3_ + c] = f2bf(acc[fi][fj][rg] + bb);
            }
    }
}

// ---------------- persistent GRU scan: 64 steps in one kernel ---------------
// 256 blocks x 512 threads (8 waves; wave owns 32 cols x 3 gates).
// R12 KEY INSIGHT (from R5-R11 VGPR grants: 36KB->128, 62KB/1024t->64,
// 62KB/512t->128, 45KB->128): the allocator sets its occupancy target from
// how many blocks fit by LDS, then divides the 2048-reg file. All >200-VGPR
// kernels in the guide use >80 KB LDS (single-block/CU). So: LDS = 84.3 KB
// via a TRIPLE-buffered XP pipeline (prefetch distance 3) -> 1 block/CU ->
// 8-wave target -> 256-VGPR budget -> the 192-reg Wh tile finally fits.
// Wh loads volatile (R10) so they cannot be rematerialized into the loop.
__global__ __launch_bounds__(512, 2) void k_scan(
    const int* __restrict__ tokens,      // [4096][64]
    const u16* __restrict__ XPROJ,       // [32000][768]
    const u16* __restrict__ Wh,          // [768][256]
    const float* __restrict__ bhh,
    float* __restrict__ HA)              // [4096][512], writes cols 0..255
{
    __shared__ __align__(16) u16 hS[16 * RH_];          // 8 KB, swizzled
    __shared__ __align__(16) u16 XPs[3][3 * 16 * 256];  // 3 x 24 KB gate-major
    __shared__ int toks[16 * 68];                       // padded rows, 4.25 KB

    const int tid = threadIdx.x;
    const int n0 = blockIdx.x * 16;
    const int lane = tid & 63, wave = tid >> 6;
    const int l15 = lane & 15, l4 = lane >> 4;
    const int c0w = wave * 32;

    // prologue: tokens -> LDS [row][68]; zero hS
    for (int idx = tid; idx < 16 * TT_; idx += 512) {
        int row = idx >> 6, tt = idx & 63;
        toks[row * 68 + tt] = tokens[(n0 + row) * TT_ + tt];
    }
    ((unsigned long long*)hS)[tid] = 0ull;
    ((unsigned long long*)hS)[512 + tid] = 0ull;

    // Wh -> VGPRs: 3 gates x 2 col-frags x 8 k-chunks = 48 frags = 192 VGPR.
    // Volatile: cannot be rematerialized/duplicated into the loop.
    bf16x8 Bv[3][2][8];
#pragma unroll
    for (int g = 0; g < 3; ++g)
#pragma unroll
        for (int f = 0; f < 2; ++f)
#pragma unroll
            for (int ks = 0; ks < 8; ++ks) {
                const volatile u32x4v* p = (const volatile u32x4v*)(
                    Wh + (size_t)(g * 256 + c0w + f * 16 + l15) * RH_ + ks * 32 + l4 * 8);
                u32x4v raw = *p;
                Bv[g][f][ks] = __builtin_bit_cast(bf16x8, raw);
            }

    const float bhn0 = bhh[512 + c0w + l15];
    const float bhn1 = bhh[512 + c0w + 16 + l15];

    // XP DMA map: thread -> (row = tid>>5, 16B chunk = tid&31) per gate.
    // Dest linear; source pre-swizzled to match gate-read swizzle (rule 21).
    const int srow = tid >> 5, sch = tid & 31;
    const int ssw = (((sch * 16) ^ ((srow >> 2) << 5)) >> 1);  // u16 units

    auto STAGE_XP = [&](int t, int b) {
        int tok = toks[srow * 68 + t];
        const u16* src = XPROJ + (size_t)tok * G3_ + ssw;
#pragma unroll
        for (int g = 0; g < 3; ++g)
            gload16(src + g * 256, &XPs[b][g * 4096 + tid * 8]);
    };

    __syncthreads();   // toks + hS zero visible to all waves

    STAGE_XP(0, 0);
    STAGE_XP(1, 1);
    STAGE_XP(2, 2);

    f32x4 hprev[2] = {};
    int bcur = 0;      // rotating buffer index = t % 3

#pragma unroll 1
    for (int t = 0; t < TT_; ++t) {
        // ---- recurrent GEMM: gh = h @ Wh^T (A from swizzled hS, B resident) ----
        f32x4 acc[3][2];
#pragma unroll
        for (int g = 0; g < 3; ++g) { acc[g][0] = f32x4{}; acc[g][1] = f32x4{}; }
#pragma unroll
        for (int ks = 0; ks < 8; ++ks) {
            const int aa = (l15 * 512 + ks * 64 + l4 * 16) ^ ((l15 & 7) << 4);
            bf16x8 a = *(const bf16x8*)((const char*)hS + aa);
#pragma unroll
            for (int g = 0; g < 3; ++g) {
                acc[g][0] = MFMA16(a, Bv[g][0][ks], acc[g][0], 0, 0, 0);
                acc[g][1] = MFMA16(a, Bv[g][1][ks], acc[g][1], 0, 0, 0);
            }
        }
        __syncthreads();   // hS reads done; XPs[bcur] DMA fully drained

        // ---- gate math (XP from gate-major swizzled LDS buffer bcur) ----
        const u16* XB = XPs[bcur];
#pragma unroll
        for (int f = 0; f < 2; ++f) {
            const int cc = c0w + f * 16 + l15;     // 0..255
            const float bhn = f == 0 ? bhn0 : bhn1;
#pragma unroll
            for (int rg = 0; rg < 4; ++rg) {
                const int r = l4 * 4 + rg;
                const int xb = r * 256 + ((((cc * 2) ^ ((r >> 2) << 5))) >> 1);
                float xr = bf2f(XB[xb]);
                float xz = bf2f(XB[4096 + xb]);
                float xn = bf2f(XB[8192 + xb]);
                float rr = 1.f / (1.f + __expf(-(xr + acc[0][f][rg])));
                float zz = 1.f / (1.f + __expf(-(xz + acc[1][f][rg])));
                float pre = xn + rr * (acc[2][f][rg] + bhn);
                float nv = 2.f / (1.f + __expf(-2.f * pre)) - 1.f;
                float hnew = nv + zz * (hprev[f][rg] - nv);
                hprev[f][rg] = hnew;
                if (t < TT_ - 1) {
                    const int ba = (r * 512 + cc * 2) ^ ((r & 7) << 4);
                    *(u16*)((char*)hS + ba) = f2bf(hnew);
                } else {
                    HA[(size_t)(n0 + r) * 512 + cc] = hnew;
                }
            }
        }
        __syncthreads();   // XPs[bcur]/hS consumers done; buffer reusable
        if (t + 3 < TT_) STAGE_XP(t + 3, bcur);
        bcur = (bcur == 2) ? 0 : bcur + 1;
    }
}

// ---------------- backward GRU single cell (x-part only, h0=0) --------------
template<bool XONLY>
__global__ __launch_bounds__(256) void k_step(
    const int* __restrict__ tokens, int t,
    const u16* __restrict__ embbf, const u16* __restrict__ Wx,
    const u16* __restrict__ Wh,
    const float* __restrict__ bih, const float* __restrict__ bhh,
    const u16* __restrict__ hbf_in, const float* __restrict__ hf_in,
    float* __restrict__ outf, int ostride, u16* __restrict__ outbf)
{
    constexpr int NSX = DINP / 32;
    constexpr int NS  = XONLY ? NSX : NSX + RH_ / 32;

    __shared__ __align__(16) u16 As[2][32 * 32];
    __shared__ __align__(16) u16 Bs[2][3 * 64 * 32];

    const int tid = threadIdx.x;
    const int n0 = blockIdx.x * 32;
    const int c0 = blockIdx.y * 64;

    const int sr = tid >> 2;
    const int sq = tid & 3;
    const int tok = (tid < 128) ? tokens[(n0 + sr) * TT_ + t] : 0;
    const u16* ax  = embbf + (size_t)tok * DINP + sq * 8;
    const u16* ah  = XONLY ? ax : hbf_in + (size_t)(n0 + sr) * RH_ + sq * 8;
    const u16* bx0 = Wx + (size_t)(0 * 256 + c0 + sr) * DINP + sq * 8;
    const u16* bx1 = Wx + (size_t)(1 * 256 + c0 + sr) * DINP + sq * 8;
    const u16* bx2 = Wx + (size_t)(2 * 256 + c0 + sr) * DINP + sq * 8;
    const u16* bh0 = XONLY ? ax : Wh + (size_t)(0 * 256 + c0 + sr) * RH_ + sq * 8;
    const u16* bh1 = XONLY ? ax : Wh + (size_t)(1 * 256 + c0 + sr) * RH_ + sq * 8;
    const u16* bh2 = XONLY ? ax : Wh + (size_t)(2 * 256 + c0 + sr) * RH_ + sq * 8;

    auto STAGE = [&](int b, int s) {
        u16* db = &Bs[b][tid * 8];
        if (s < NSX) {
            int kk = s * 32;
            if (tid < 128) gload16(ax + kk, &As[b][tid * 8]);
            gload16(bx0 + kk, db);
            gload16(bx1 + kk, db + 2048);
            gload16(bx2 + kk, db + 4096);
        } else {
            int kk = (s - NSX) * 32;
            if (tid < 128) gload16(ah + kk, &As[b][tid * 8]);
            gload16(bh0 + kk, db);
            gload16(bh1 + kk, db + 2048);
            gload16(bh2 + kk, db + 4096);
        }
    };

    const int lane = tid & 63;
    const int wave = tid >> 6;
    const int wr = wave >> 1, wc = wave & 1;
    const int l15 = lane & 15, l4 = lane >> 4;

    f32x4 aR[2] = {}, aZ[2] = {}, aXN[2] = {}, aHN[2] = {};

    const int aoff = (wr * 16 + l15) * 32 + l4 * 8;
    const int boff = (wc * 32 + l15) * 32 + l4 * 8;

    auto COMPUTE = [&](int b, bool xp) {
        bf16x8 a0 = *(const bf16x8*)&As[b][aoff];
        const u16* B = &Bs[b][0];
        bf16x8 r0 = *(const bf16x8*)&B[boff];
        bf16x8 r1 = *(const bf16x8*)&B[boff + 512];
        bf16x8 z0 = *(const bf16x8*)&B[2048 + boff];
        bf16x8 z1 = *(const bf16x8*)&B[2048 + boff + 512];
        bf16x8 n0f = *(const bf16x8*)&B[4096 + boff];
        bf16x8 n1f = *(const bf16x8*)&B[4096 + boff + 512];
        aR[0] = MFMA16(a0, r0, aR[0], 0, 0, 0);
        aR[1] = MFMA16(a0, r1, aR[1], 0, 0, 0);
        aZ[0] = MFMA16(a0, z0, aZ[0], 0, 0, 0);
        aZ[1] = MFMA16(a0, z1, aZ[1], 0, 0, 0);
        if (xp) {
            aXN[0] = MFMA16(a0, n0f, aXN[0], 0, 0, 0);
            aXN[1] = MFMA16(a0, n1f, aXN[1], 0, 0, 0);
        } else {
            aHN[0] = MFMA16(a0, n0f, aHN[0], 0, 0, 0);
            aHN[1] = MFMA16(a0, n1f, aHN[1], 0, 0, 0);
        }
    };

    STAGE(0, 0);
    __syncthreads();
#pragma unroll
    for (int s = 0; s < NS; ++s) {
        if (s + 1 < NS) STAGE((s + 1) & 1, s + 1);
        COMPUTE(s & 1, s < NSX);
        __syncthreads();
    }

#pragma unroll
    for (int fj = 0; fj < 2; ++fj) {
        const int c = c0 + wc * 32 + fj * 16 + l15;
        const float bR  = bih[c] + bhh[c];
        const float bZ  = bih[256 + c] + bhh[256 + c];
        const float bXN = bih[512 + c];
        const float bHN = bhh[512 + c];
#pragma unroll
        for (int rg = 0; rg < 4; ++rg) {
            const int n = n0 + wr * 16 + l4 * 4 + rg;
            float r  = 1.f / (1.f + __expf(-(aR[fj][rg] + bR)));
            float z  = 1.f / (1.f + __expf(-(aZ[fj][rg] + bZ)));
            float pre = aXN[fj][rg] + bXN + r * (aHN[fj][rg] + bHN);
            float nv = 2.f / (1.f + __expf(-2.f * pre)) - 1.f;
            float hp = XONLY ? 0.f : hf_in[(size_t)n * RH_ + c];
            float h  = (1.f - z) * nv + z * hp;
            outf[(size_t)n * ostride + c] = h;
            if (!XONLY) outbf[(size_t)n * RH_ + c] = f2bf(h);
        }
    }
}

// ---------------- block-diag aggregation: agg_g = A_g @ h_g (bf16 MFMA) -----
__global__ __launch_bounds__(256) void k_agg(
    const u16* __restrict__ Abf, const u16* __restrict__ hT,
    u16* __restrict__ aggbf, int C)
{
    const int g = blockIdx.x, ct = blockIdx.y;
    const int lane = threadIdx.x & 63, wave = threadIdx.x >> 6;
    const int wi = wave >> 1, wcC = wave & 1;
    const int l15 = lane & 15, l4 = lane >> 4;
    f32x4 acc[2][2] = {};
#pragma unroll
    for (int kc = 0; kc < 2; kc++) {
        bf16x8 af[2], bf_[2];
#pragma unroll
        for (int fi = 0; fi < 2; fi++)
            af[fi] = *(const bf16x8*)(Abf + ((size_t)g * 64 + wi * 32 + fi * 16 + l15) * 64
                                      + kc * 32 + l4 * 8);
#pragma unroll
        for (int fj = 0; fj < 2; fj++)
            bf_[fj] = *(const bf16x8*)(hT + (size_t)(ct * 64 + wcC * 32 + fj * 16 + l15) * NN_
                                       + g * 64 + kc * 32 + l4 * 8);
#pragma unroll
        for (int fi = 0; fi < 2; fi++)
#pragma unroll
            for (int fj = 0; fj < 2; fj++)
                acc[fi][fj] = MFMA16(af[fi], bf_[fj], acc[fi][fj], 0, 0, 0);
    }
#pragma unroll
    for (int fi = 0; fi < 2; fi++)
#pragma unroll
        for (int fj = 0; fj < 2; fj++)
#pragma unroll
            for (int rg = 0; rg < 4; rg++) {
                int n = g * 64 + wi * 32 + fi * 16 + l4 * 4 + rg;
                int c = ct * 64 + wcC * 32 + fj * 16 + l15;
                aggbf[(size_t)n * C + c] = f2bf(acc[fi][fj][rg]);
            }
}

// ---------------- GCN GEMM (bf16 MFMA): out = relu(agg @ W + b) -------------
template<int K>
__global__ __launch_bounds__(256) void k_gcnM(
    const u16* __restrict__ Ag, const u16* __restrict__ Wt,
    const float* __restrict__ bias, float* __restrict__ outF)
{
    __shared__ __align__(16) u16 As[2][64 * 32];
    __shared__ __align__(16) u16 Bs[2][64 * 32];
    const int tid = threadIdx.x;
    const int n0 = blockIdx.x * 64, c0 = blockIdx.y * 64;
    const int sr = tid >> 2, sq = tid & 3;
    const u16* pa = Ag + (size_t)(n0 + sr) * K + sq * 8;
    const u16* pb = Wt + (size_t)(c0 + sr) * K + sq * 8;

    const int lane = tid & 63, wave = tid >> 6;
    const int wr = wave >> 1, wc = wave & 1;
    const int l15 = lane & 15, l4 = lane >> 4;
    const int aoff = (wr * 32 + l15) * 32 + l4 * 8;
    const int boff = (wc * 32 + l15) * 32 + l4 * 8;
    f32x4 acc[2][2] = {};

    gload16(pa, &As[0][tid * 8]);
    gload16(pb, &Bs[0][tid * 8]);
    __syncthreads();
    constexpr int NSK = K / 32;
#pragma unroll
    for (int s = 0; s < NSK; s++) {
        if (s + 1 < NSK) {
            gload16(pa + (s + 1) * 32, &As[(s + 1) & 1][tid * 8]);
            gload16(pb + (s + 1) * 32, &Bs[(s + 1) & 1][tid * 8]);
        }
        const int b = s & 1;
        bf16x8 a0 = *(const bf16x8*)&As[b][aoff];
        bf16x8 a1 = *(const bf16x8*)&As[b][aoff + 512];
        bf16x8 b0 = *(const bf16x8*)&Bs[b][boff];
        bf16x8 b1 = *(const bf16x8*)&Bs[b][boff + 512];
        acc[0][0] = MFMA16(a0, b0, acc[0][0], 0, 0, 0);
        acc[0][1] = MFMA16(a0, b1, acc[0][1], 0, 0, 0);
        acc[1][0] = MFMA16(a1, b0, acc[1][0], 0, 0, 0);
        acc[1][1] = MFMA16(a1, b1, acc[1][1], 0, 0, 0);
        __syncthreads();
    }
#pragma unroll
    for (int fj = 0; fj < 2; fj++) {
        const int c = c0 + wc * 32 + fj * 16 + l15;
        const float bb = bias[c];
#pragma unroll
        for (int fi = 0; fi < 2; fi++)
#pragma unroll
            for (int rg = 0; rg < 4; rg++) {
                const int n = n0 + wr * 32 + fi * 16 + l4 * 4 + rg;
                outF[(size_t)n * 256 + c] = fmaxf(acc[fi][fj][rg] + bb, 0.f);
            }
    }
}

// ---------------- readout ----------------
__global__ void k_readout(const float* __restrict__ h, const int* __restrict__ gid,
                          const int* __restrict__ ntype, float* __restrict__ out,
                          float* __restrict__ cnt)
{
    for (int idx = blockIdx.x * blockDim.x + threadIdx.x; idx < NN_ * 256;
         idx += gridDim.x * blockDim.x) {
        int n = idx >> 8, c = idx & 255;
        float v = h[idx];
        int g = gid[n], t = ntype[n];
        if (t == 0) {
            atomicAdd(&out[g * 256 + c], v);
            if (c == 0) atomicAdd(&cnt[g], 1.f);
        } else if (t == 1) {
            atomicAdd(&out[16384 + g * 256 + c], v);
        } else {
            atomicAdd(&out[32768 + g * 256 + c], v);
        }
    }
}

__global__ void k_finalize(float* __restrict__ out, const float* __restrict__ cnt)
{
    int idx = blockIdx.x * blockDim.x + threadIdx.x;  // < 16384
    out[idx] /= cnt[idx >> 8];
}

// ---------------- host ----------------
extern "C" void kernel_launch(void* const* d_in, const int* in_sizes, int n_in,
                              void* d_out, int out_size, void* d_ws, size_t ws_size,
                              hipStream_t stream)
{
    const int*   tokens = (const int*)d_in[0];
    const int*   esrc   = (const int*)d_in[1];
    const int*   edst   = (const int*)d_in[2];
    const int*   gid    = (const int*)d_in[3];
    const int*   ntype  = (const int*)d_in[4];
    const float* emb    = (const float*)d_in[5];
    const float* W_ih_f = (const float*)d_in[6];
    const float* W_hh_f = (const float*)d_in[7];
    const float* b_ih_f = (const float*)d_in[8];
    const float* b_hh_f = (const float*)d_in[9];
    const float* W_ih_b = (const float*)d_in[10];
    const float* b_ih_b = (const float*)d_in[12];
    const float* b_hh_b = (const float*)d_in[13];
    const float* Wg[4]  = {(const float*)d_in[14], (const float*)d_in[16],
                           (const float*)d_in[18], (const float*)d_in[20]};
    const float* bg[4]  = {(const float*)d_in[15], (const float*)d_in[17],
                           (const float*)d_in[19], (const float*)d_in[21]};
    float* out = (float*)d_out;

    // workspace layout (16B aligned).
    // Af overlays hF (Af: prologue only; hF first written after scan).
    // hT + aggb overlay XPROJ's head (XPROJ dead after k_scan).
    float* hF    = (float*)d_ws;                        // [4096][256] f32
    float* Af    = hF;                                  // [64][64][64] f32 (prologue)
    u16*   embbf = (u16*)(hF + (size_t)NN_ * RH_);      // [32000][320]
    u16*   wxf   = embbf + 32000L * DINP;               // [768][320]
    u16*   whf   = wxf + (size_t)G3_ * DINP;            // [768][256]
    u16*   wxb   = whf + (size_t)G3_ * RH_;             // [768][320]
    u16*   wtg   = wxb + (size_t)G3_ * DINP;            // [256][512] max
    u16*   Abf   = wtg + 256L * 512;                    // [64][64][64]
    u16*   XPROJ = Abf + 64L * 64 * 64;                 // [32000][768]
    u16*   hT    = XPROJ;                               // [512][4096] (post-scan)
    u16*   aggb  = hT + 512L * NN_;                     // [4096][512] (post-scan)
    float* HA    = (float*)(XPROJ + 32000L * G3_);      // [4096][512] f32
    float* CNT   = HA + (size_t)NN_ * 512;              // [64]

    // one-time conversions + adjacency build
    k_cvt<<<2048, 256, 0, stream>>>(emb, embbf, 32000, DIN, DINP);
    k_cvt<<<256, 256, 0, stream>>>(W_ih_f, wxf, G3_, DIN, DINP);
    k_cvt<<<256, 256, 0, stream>>>(W_hh_f, whf, G3_, RH_, RH_);
    k_cvt<<<256, 256, 0, stream>>>(W_ih_b, wxb, G3_, DIN, DINP);
    k_zero<<<256, 256, 0, stream>>>(Af, 64L * 64 * 64);
    k_buildA<<<256, 256, 0, stream>>>(esrc, edst, Af);
    k_cvt<<<256, 256, 0, stream>>>(Af, Abf, 64 * 64, 64, 64);

    // XPROJ table then the whole forward scan in ONE kernel
    k_xproj<<<dim3(500, 12), 256, 0, stream>>>(embbf, wxf, b_ih_f, b_hh_f, XPROJ);
    k_scan<<<256, 512, 0, stream>>>(tokens, XPROJ, whf, b_hh_f, HA);

    // backward GRU single cell on x[:,T-1] -> HA cols 256..511
    k_step<true><<<dim3(128, 4), 256, 0, stream>>>(
        tokens, TT_ - 1, embbf, wxb, nullptr, b_ih_b, b_hh_b,
        nullptr, nullptr, HA + 256, 512, nullptr);

    // GCN: hT <- transpose(h); agg <- blockdiag(A) @ h; h <- relu(agg @ W + b)
    k_trans<<<dim3(64, 8), 256, 0, stream>>>(HA, 512, hT);
    for (int l = 0; l < 4; l++) {
        int K = (l == 0) ? 512 : 256;
        k_cvtT<<<128, 256, 0, stream>>>(Wg[l], wtg, K);
        k_agg<<<dim3(64, K / 64), 256, 0, stream>>>(Abf, hT, aggb, K);
        if (K == 512)
            k_gcnM<512><<<dim3(64, 4), 256, 0, stream>>>(aggb, wtg, bg[l], hF);
        else
            k_gcnM<256><<<dim3(64, 4), 256, 0, stream>>>(aggb, wtg, bg[l], hF);
        if (l < 3) k_trans<<<dim3(64, 4), 256, 0, stream>>>(hF, 256, hT);
    }

    // readout
    k_zero<<<256, 256, 0, stream>>>(out, 49152);
    k_zero<<<1, 64, 0, stream>>>(CNT, 64);
    k_readout<<<2048, 256, 0, stream>>>(hF, gid, ntype, out, CNT);
    k_finalize<<<64, 256, 0, stream>>>(out, CNT);
}